// Round 1
// baseline (684.091 us; speedup 1.0000x reference)
//
#include <hip/hip_runtime.h>
#include <cstdint>
#include <cstddef>

typedef __attribute__((ext_vector_type(8))) short frag8;
typedef __attribute__((ext_vector_type(4))) float f32x4;

static __device__ __forceinline__ unsigned short f2bf(float f) {
    unsigned int u = __float_as_uint(f);
    u += 0x7fffu + ((u >> 16) & 1u);
    return (unsigned short)(u >> 16);
}

#define BM 128
#define BN 128
#define BK 32
#define LDST 40   // 32 + 8 pad: breaks 64B-row bank aliasing for ds_read_b128

// C[M,N] = act(A[M,K] @ Bt[N,K]^T + bias)
// A row-major (fp32 or bf16-as-ushort), Bt row-major bf16 [N][K].
// CORR mode: blockIdx.z = dz*4 + ksplit; delta = dz-4; B's K index is
// circularly shifted by -256*delta (mod Kmask+1); output goes to
// partial[z][Mfull][ldC] fp32.
template<bool A_FP32, bool RELU, bool BIAS, bool OUT_BF16, bool CORR>
__global__ __launch_bounds__(256, 2)
void gemm_bt(const void* __restrict__ Av, const unsigned short* __restrict__ Bt,
             const float* __restrict__ bias, void* __restrict__ Cv,
             int ldA, int ldB, int ldC, int kLen, int Kmask, int Mfull)
{
    __shared__ unsigned short As[BM * LDST];
    __shared__ unsigned short Bs[BN * LDST];

    const int t    = threadIdx.x;
    const int wave = t >> 6;
    const int lane = t & 63;
    const int quad = lane >> 4;
    const int l15  = lane & 15;
    const int wm   = (wave >> 1) * 64;
    const int wn   = (wave & 1) * 64;
    const int m0   = blockIdx.y * BM;
    const int n0   = blockIdx.x * BN;

    int kStart = 0, koff = 0;
    if (CORR) {
        const int z = blockIdx.z;
        kStart = (z & 3) * kLen;
        const int delta = (z >> 2) - 4;           // -4..4
        koff = ((Kmask + 1) - 256 * delta) & Kmask;
    }

    f32x4 acc[4][4];
    #pragma unroll
    for (int i = 0; i < 4; ++i)
        #pragma unroll
        for (int j = 0; j < 4; ++j)
            acc[i][j] = (f32x4){0.f, 0.f, 0.f, 0.f};

    for (int k0 = 0; k0 < kLen; k0 += BK) {
        // ---- stage A tile [128 x 32] ----
        if (A_FP32) {
            const float* A = (const float*)Av;
            #pragma unroll
            for (int p = 0; p < 4; ++p) {
                int idx = p * 256 + t;
                int row = idx >> 3;
                int col = (idx & 7) * 4;
                const float4 v = *(const float4*)(A + (size_t)(m0 + row) * ldA + (kStart + k0 + col));
                unsigned int u0 = (unsigned int)f2bf(v.x) | ((unsigned int)f2bf(v.y) << 16);
                unsigned int u1 = (unsigned int)f2bf(v.z) | ((unsigned int)f2bf(v.w) << 16);
                uint2 pk; pk.x = u0; pk.y = u1;
                *(uint2*)&As[row * LDST + col] = pk;   // 8B aligned: row*80 + col*2
            }
        } else {
            const unsigned short* A = (const unsigned short*)Av;
            #pragma unroll
            for (int p = 0; p < 2; ++p) {
                int idx = p * 256 + t;
                int row = idx >> 2;
                int col = (idx & 3) * 8;
                uint4 v = *(const uint4*)(A + (size_t)(m0 + row) * ldA + (kStart + k0 + col));
                *(uint4*)&As[row * LDST + col] = v;    // 16B aligned
            }
        }
        // ---- stage B tile [128 x 32] (bf16, optional circular K shift) ----
        #pragma unroll
        for (int p = 0; p < 2; ++p) {
            int idx = p * 256 + t;
            int row = idx >> 2;
            int col = (idx & 3) * 8;
            int kg = (kStart + k0 + col + koff) & Kmask;   // pow2 K: exact mod
            uint4 v = *(const uint4*)(Bt + (size_t)(n0 + row) * ldB + kg);
            *(uint4*)&Bs[row * LDST + col] = v;
        }
        __syncthreads();

        frag8 af[4], bfr[4];
        #pragma unroll
        for (int i = 0; i < 4; ++i)
            af[i] = *(const frag8*)&As[(wm + i * 16 + l15) * LDST + quad * 8];
        #pragma unroll
        for (int j = 0; j < 4; ++j)
            bfr[j] = *(const frag8*)&Bs[(wn + j * 16 + l15) * LDST + quad * 8];
        #pragma unroll
        for (int i = 0; i < 4; ++i)
            #pragma unroll
            for (int j = 0; j < 4; ++j)
                acc[i][j] = __builtin_amdgcn_mfma_f32_16x16x32_bf16(af[i], bfr[j], acc[i][j], 0, 0, 0);
        __syncthreads();
    }

    // ---- epilogue ----
    if (CORR) {
        float* C = (float*)Cv + (size_t)blockIdx.z * (size_t)Mfull * (size_t)ldC;
        #pragma unroll
        for (int i = 0; i < 4; ++i) {
            int rg = m0 + wm + i * 16 + quad * 4;
            #pragma unroll
            for (int j = 0; j < 4; ++j) {
                int cg = n0 + wn + j * 16 + l15;
                #pragma unroll
                for (int r = 0; r < 4; ++r)
                    C[(size_t)(rg + r) * ldC + cg] = acc[i][j][r];
            }
        }
    } else {
        #pragma unroll
        for (int i = 0; i < 4; ++i) {
            int rg = m0 + wm + i * 16 + quad * 4;
            #pragma unroll
            for (int j = 0; j < 4; ++j) {
                int cg = n0 + wn + j * 16 + l15;
                float bv = BIAS ? bias[cg] : 0.0f;
                #pragma unroll
                for (int r = 0; r < 4; ++r) {
                    float val = acc[i][j][r] + bv;
                    if (RELU) val = fmaxf(val, 0.0f);
                    if (OUT_BF16)
                        ((unsigned short*)Cv)[(size_t)(rg + r) * ldC + cg] = f2bf(val);
                    else
                        ((float*)Cv)[(size_t)(rg + r) * ldC + cg] = val;
                }
            }
        }
    }
}

// dst[N][R] bf16 <- src[R][N] fp32 (weight transpose+convert; tiny)
__global__ void transp_bf16(const float* __restrict__ src, unsigned short* __restrict__ dst,
                            int R, int C) {
    int i = blockIdx.x * blockDim.x + threadIdx.x;
    if (i >= R * C) return;
    int r = i % R;
    int n = i / R;
    dst[(size_t)n * R + r] = f2bf(src[(size_t)r * C + n]);
}

// out[q,c] = max_dz sum_ks partial[(dz*4+ks)][q*512+c]
__global__ void reduce_max9(const float* __restrict__ partial, float* __restrict__ out) {
    int idx = blockIdx.x * blockDim.x + threadIdx.x;   // 0..262143
    float best = -3.4e38f;
    #pragma unroll
    for (int dz = 0; dz < 9; ++dz) {
        float s = 0.f;
        #pragma unroll
        for (int ks = 0; ks < 4; ++ks)
            s += partial[((size_t)(dz * 4 + ks) << 18) + idx];
        best = fmaxf(best, s);
    }
    out[idx] = best;
}

extern "C" void kernel_launch(void* const* d_in, const int* in_sizes, int n_in,
                              void* d_out, int out_size, void* d_ws, size_t ws_size,
                              hipStream_t stream) {
    const float* audio = (const float*)d_in[0];   // [512,128,512]
    const float* video = (const float*)d_in[1];   // [512,128,512]
    const float* a_w1  = (const float*)d_in[2];   // [512,256]
    const float* a_b1  = (const float*)d_in[3];
    const float* a_w2  = (const float*)d_in[4];   // [256,256]
    const float* a_b2  = (const float*)d_in[5];
    const float* v_w1  = (const float*)d_in[6];
    const float* v_b1  = (const float*)d_in[7];
    const float* v_w2  = (const float*)d_in[8];
    const float* v_b2  = (const float*)d_in[9];
    const float* Wm    = (const float*)d_in[10];  // [256,256]

    char* ws = (char*)d_ws;
    // ws layout (bytes):
    unsigned short* aw1T = (unsigned short*)(ws + 0);          // [256][512]
    unsigned short* aw2T = (unsigned short*)(ws + 262144);     // [256][256]
    unsigned short* vw1T = (unsigned short*)(ws + 393216);     // [256][512]
    unsigned short* vw2T = (unsigned short*)(ws + 655360);     // [256][256]
    unsigned short* WT   = (unsigned short*)(ws + 786432);     // [256][256]
    unsigned short* a_bf = (unsigned short*)(ws + 1048576);    // [512,32768] = a  (33.5 MB, live->corr)
    unsigned short* pv   = (unsigned short*)(ws + 34603008);   // [512,32768] = pv (33.5 MB, live->corr)
    unsigned short* hbuf = (unsigned short*)(ws + 68157440);   // h_a then h_v (33.5 MB)
    unsigned short* vbuf = (unsigned short*)(ws + 101711872);  // v (33.5 MB)
    float* partial = (float*)(ws + 68157440);                  // [36][512][512] fp32 (37.75 MB, over dead h/v)
    float* out = (float*)d_out;

    // weight transposes (fp32 -> bf16 [N][K])
    transp_bf16<<<dim3(512), 256, 0, stream>>>(a_w1, aw1T, 512, 256);
    transp_bf16<<<dim3(256), 256, 0, stream>>>(a_w2, aw2T, 256, 256);
    transp_bf16<<<dim3(512), 256, 0, stream>>>(v_w1, vw1T, 512, 256);
    transp_bf16<<<dim3(256), 256, 0, stream>>>(v_w2, vw2T, 256, 256);
    transp_bf16<<<dim3(256), 256, 0, stream>>>(Wm,   WT,   256, 256);

    // audio MLP: h = relu(audio@w1+b1) ; a = h@w2+b2
    gemm_bt<true,  true,  true,  true, false><<<dim3(2, 512), 256, 0, stream>>>(
        audio, aw1T, a_b1, hbuf, 512, 512, 256, 512, 511, 0);
    gemm_bt<false, false, true,  true, false><<<dim3(2, 512), 256, 0, stream>>>(
        hbuf, aw2T, a_b2, a_bf, 256, 256, 256, 256, 255, 0);

    // video MLP + projection: v = mlp(video) ; pv = v@W
    gemm_bt<true,  true,  true,  true, false><<<dim3(2, 512), 256, 0, stream>>>(
        video, vw1T, v_b1, hbuf, 512, 512, 256, 512, 511, 0);
    gemm_bt<false, false, true,  true, false><<<dim3(2, 512), 256, 0, stream>>>(
        hbuf, vw2T, v_b2, vbuf, 256, 256, 256, 256, 255, 0);
    gemm_bt<false, false, false, true, false><<<dim3(2, 512), 256, 0, stream>>>(
        vbuf, WT, nullptr, pv, 256, 256, 256, 256, 255, 0);

    // lag correlation: partial[dz*4+ks][q][c] over K chunks of 8192
    gemm_bt<false, false, false, false, true><<<dim3(4, 4, 36), 256, 0, stream>>>(
        a_bf, pv, nullptr, partial, 32768, 32768, 512, 8192, 32767, 512);

    // sum split-K, max over deltas
    reduce_max9<<<dim3(1024), 256, 0, stream>>>(partial, out);
}

// Round 2
// 586.020 us; speedup vs baseline: 1.1673x; 1.1673x over previous
//
#include <hip/hip_runtime.h>
#include <cstdint>
#include <cstddef>

typedef __attribute__((ext_vector_type(8))) short frag8;
typedef __attribute__((ext_vector_type(4))) float f32x4;

static __device__ __forceinline__ unsigned short f2bf(float f) {
    unsigned int u = __float_as_uint(f);
    u += 0x7fffu + ((u >> 16) & 1u);
    return (unsigned short)(u >> 16);
}

// async global->LDS, 16B per lane. LDS dest = wave-uniform base + lane*16.
static __device__ __forceinline__ void gll16(const void* g, void* l) {
    __builtin_amdgcn_global_load_lds(
        (const __attribute__((address_space(1))) unsigned int*)g,
        (__attribute__((address_space(3))) unsigned int*)l, 16, 0, 0);
}

// C[M,N] = act(A[M,K] @ Bt[N,K]^T + bias)
// AMODE 0: A fp32, manual staging w/ convert (padded LDS). AMODE 1: A bf16 via
// global_load_lds into swizzled granule layout s = row*4 + (quad ^ ((row>>1)&3)).
// B always bf16 [N][K] via global_load_lds (swizzled).
// CORR: blockIdx.z = dz*4+ksplit; delta=dz-4; B k-index circularly shifted.
template<int AMODE, bool RELU, bool BIAS, bool OUT_BF16, bool CORR>
__global__ __launch_bounds__(256, 3)
void gemm_bt2(const void* __restrict__ Av, const unsigned short* __restrict__ Bt,
              const float* __restrict__ bias, void* __restrict__ Cv,
              int ldA, int ldB, int ldC, int kLen, int Kmask, int Mfull)
{
    __shared__ unsigned short As[(AMODE == 0) ? 128 * 40 : 128 * 32];
    __shared__ unsigned short Bs[128 * 32];

    const int t    = threadIdx.x;
    const int wave = t >> 6;
    const int lane = t & 63;
    const int quad = lane >> 4;
    const int l15  = lane & 15;
    const int wm   = (wave >> 1) * 64;
    const int wn   = (wave & 1) * 64;
    const int m0   = blockIdx.y * 128;
    const int n0   = blockIdx.x * 128;

    int kStart = 0, koff = 0;
    if (CORR) {
        const int z = blockIdx.z;
        kStart = (z & 3) * kLen;
        const int delta = (z >> 2) - 4;           // -4..4
        koff = ((Kmask + 1) - 256 * delta) & Kmask;
    }

    // gll lane->granule mapping: slot s = wave*128 + p*64 + lane
    // row = s>>2; g = s&3; src quad = g ^ ((row>>1)&3)
    const int rowL = (wave << 5) + (lane >> 2);             // row for p=0 (p=1: +16, same quad)
    const int qL   = (lane & 3) ^ ((lane >> 3) & 3);
    const size_t offB0 = (size_t)(n0 + rowL) * ldB + qL * 8;
    const size_t offB1 = offB0 + (size_t)16 * ldB;
    const size_t offA0 = (size_t)(m0 + rowL) * ldA + qL * 8;
    const size_t offA1 = offA0 + (size_t)16 * ldA;
    const int swz = quad ^ ((l15 >> 1) & 3);                // read-side swizzle

    f32x4 acc[4][4];
    #pragma unroll
    for (int i = 0; i < 4; ++i)
        #pragma unroll
        for (int j = 0; j < 4; ++j)
            acc[i][j] = (f32x4){0.f, 0.f, 0.f, 0.f};

    for (int k0 = 0; k0 < kLen; k0 += 32) {
        // ---- stage B [128x32] bf16 via global_load_lds ----
        const int kB = (k0 + kStart + koff) & Kmask;
        gll16(Bt + offB0 + kB, &Bs[wave * 1024]);
        gll16(Bt + offB1 + kB, &Bs[wave * 1024 + 512]);
        // ---- stage A [128x32] ----
        if (AMODE == 1) {
            const unsigned short* A = (const unsigned short*)Av;
            const int kA = kStart + k0;
            gll16(A + offA0 + kA, &As[wave * 1024]);
            gll16(A + offA1 + kA, &As[wave * 1024 + 512]);
        } else {
            const float* A = (const float*)Av;
            #pragma unroll
            for (int p = 0; p < 4; ++p) {
                int idx = p * 256 + t;
                int row = idx >> 3;
                int col = (idx & 7) * 4;
                const float4 v = *(const float4*)(A + (size_t)(m0 + row) * ldA + (k0 + col));
                unsigned int u0 = (unsigned int)f2bf(v.x) | ((unsigned int)f2bf(v.y) << 16);
                unsigned int u1 = (unsigned int)f2bf(v.z) | ((unsigned int)f2bf(v.w) << 16);
                uint2 pk; pk.x = u0; pk.y = u1;
                *(uint2*)&As[row * 40 + col] = pk;        // 8B aligned
            }
        }
        __syncthreads();   // drains vmcnt(0): gll writes visible

        frag8 af[4], bf[4];
        #pragma unroll
        for (int i = 0; i < 4; ++i) {
            const int row = wm + i * 16 + l15;
            if (AMODE == 0)
                af[i] = *(const frag8*)&As[row * 40 + quad * 8];
            else
                af[i] = *(const frag8*)&As[(row * 4 + swz) * 8];
        }
        #pragma unroll
        for (int j = 0; j < 4; ++j) {
            const int row = wn + j * 16 + l15;
            bf[j] = *(const frag8*)&Bs[(row * 4 + swz) * 8];
        }
        #pragma unroll
        for (int i = 0; i < 4; ++i)
            #pragma unroll
            for (int j = 0; j < 4; ++j)
                acc[i][j] = __builtin_amdgcn_mfma_f32_16x16x32_bf16(af[i], bf[j], acc[i][j], 0, 0, 0);
        __syncthreads();
    }

    if (CORR) {
        float* C = (float*)Cv + (size_t)blockIdx.z * (size_t)Mfull * (size_t)ldC;
        #pragma unroll
        for (int i = 0; i < 4; ++i) {
            int rg = m0 + wm + i * 16 + quad * 4;
            #pragma unroll
            for (int j = 0; j < 4; ++j) {
                int cg = n0 + wn + j * 16 + l15;
                #pragma unroll
                for (int r = 0; r < 4; ++r)
                    C[(size_t)(rg + r) * ldC + cg] = acc[i][j][r];
            }
        }
    } else {
        #pragma unroll
        for (int i = 0; i < 4; ++i) {
            int rg = m0 + wm + i * 16 + quad * 4;
            #pragma unroll
            for (int j = 0; j < 4; ++j) {
                int cg = n0 + wn + j * 16 + l15;
                float bv = BIAS ? bias[cg] : 0.0f;
                #pragma unroll
                for (int r = 0; r < 4; ++r) {
                    float val = acc[i][j][r] + bv;
                    if (RELU) val = fmaxf(val, 0.0f);
                    if (OUT_BF16)
                        ((unsigned short*)Cv)[(size_t)(rg + r) * ldC + cg] = f2bf(val);
                    else
                        ((float*)Cv)[(size_t)(rg + r) * ldC + cg] = val;
                }
            }
        }
    }
}

// dst[C][R] bf16 <- src[R][C] fp32, LDS-tiled 32x32, coalesced both sides.
__global__ void transp_bf16(const float* __restrict__ src, unsigned short* __restrict__ dst,
                            int R, int C) {
    __shared__ float tile[32][33];
    const int bx = blockIdx.x * 32;   // C dim
    const int by = blockIdx.y * 32;   // R dim
    const int tx = threadIdx.x & 31;
    const int ty = threadIdx.x >> 5;  // 0..7
    #pragma unroll
    for (int r = ty; r < 32; r += 8)
        tile[r][tx] = src[(size_t)(by + r) * C + bx + tx];
    __syncthreads();
    #pragma unroll
    for (int c = ty; c < 32; c += 8)
        dst[(size_t)(bx + c) * R + by + tx] = f2bf(tile[tx][c]);
}

// WcT[n][k] = sum_d w2[k][d] * W[d][n]  (so pv = h@(w2@W) + b2@W)
// bc[n] = sum_d b2[d] * W[d][n]
__global__ void build_wc(const float* __restrict__ w2, const float* __restrict__ W,
                         const float* __restrict__ b2,
                         unsigned short* __restrict__ WcT, float* __restrict__ bc) {
    __shared__ float wcol[256];
    const int n = blockIdx.x, k = threadIdx.x;
    wcol[k] = W[(size_t)k * 256 + n];
    __syncthreads();
    float s = 0.f;
    #pragma unroll 8
    for (int d = 0; d < 256; ++d) s += w2[(size_t)k * 256 + d] * wcol[d];
    WcT[(size_t)n * 256 + k] = f2bf(s);
    if (k == 0) {
        float tt = 0.f;
        for (int d = 0; d < 256; ++d) tt += b2[d] * wcol[d];
        bc[n] = tt;
    }
}

// out[q,c] = max_dz sum_ks partial[(dz*4+ks)][q*512+c]
__global__ void reduce_max9(const float* __restrict__ partial, float* __restrict__ out) {
    const int idx = blockIdx.x * blockDim.x + threadIdx.x;   // 0..262143
    float best = -3.4e38f;
    #pragma unroll
    for (int dz = 0; dz < 9; ++dz) {
        float s = 0.f;
        #pragma unroll
        for (int ks = 0; ks < 4; ++ks)
            s += partial[((size_t)(dz * 4 + ks) << 18) + idx];
        best = fmaxf(best, s);
    }
    out[idx] = best;
}

extern "C" void kernel_launch(void* const* d_in, const int* in_sizes, int n_in,
                              void* d_out, int out_size, void* d_ws, size_t ws_size,
                              hipStream_t stream) {
    const float* audio = (const float*)d_in[0];   // [512,128,512]
    const float* video = (const float*)d_in[1];
    const float* a_w1  = (const float*)d_in[2];   // [512,256]
    const float* a_b1  = (const float*)d_in[3];
    const float* a_w2  = (const float*)d_in[4];   // [256,256]
    const float* a_b2  = (const float*)d_in[5];
    const float* v_w1  = (const float*)d_in[6];
    const float* v_b1  = (const float*)d_in[7];
    const float* v_w2  = (const float*)d_in[8];
    const float* v_b2  = (const float*)d_in[9];
    const float* Wm    = (const float*)d_in[10];  // [256,256]

    char* ws = (char*)d_ws;
    unsigned short* aw1T = (unsigned short*)(ws + 0);          // [256][512]
    unsigned short* aw2T = (unsigned short*)(ws + 262144);     // [256][256]
    unsigned short* vw1T = (unsigned short*)(ws + 393216);     // [256][512]
    unsigned short* WcT  = (unsigned short*)(ws + 655360);     // [256][256]
    float*          bc   = (float*)(ws + 786432);              // [256]
    unsigned short* a_bf = (unsigned short*)(ws + 1048576);    // [512][32768] bf16
    unsigned short* pv   = (unsigned short*)(ws + 34603008);   // [512][32768] bf16
    unsigned short* hbuf = (unsigned short*)(ws + 68157440);   // h (reused), dead before corr
    float* partial       = (float*)(ws + 68157440);            // [36][512][512] fp32 (37.75 MB)
    float* out = (float*)d_out;

    // weight prep
    transp_bf16<<<dim3(8, 16), 256, 0, stream>>>(a_w1, aw1T, 512, 256);
    transp_bf16<<<dim3(8, 8),  256, 0, stream>>>(a_w2, aw2T, 256, 256);
    transp_bf16<<<dim3(8, 16), 256, 0, stream>>>(v_w1, vw1T, 512, 256);
    build_wc<<<dim3(256), 256, 0, stream>>>(v_w2, Wm, v_b2, WcT, bc);

    // audio MLP
    gemm_bt2<0, true,  true,  true, false><<<dim3(2, 512), 256, 0, stream>>>(
        audio, aw1T, a_b1, hbuf, 512, 512, 256, 512, 511, 0);
    gemm_bt2<1, false, true,  true, false><<<dim3(2, 512), 256, 0, stream>>>(
        hbuf, aw2T, a_b2, a_bf, 256, 256, 256, 256, 255, 0);

    // video MLP with W folded into layer 2 (pv = h@(w2@W) + b2@W)
    gemm_bt2<0, true,  true,  true, false><<<dim3(2, 512), 256, 0, stream>>>(
        video, vw1T, v_b1, hbuf, 512, 512, 256, 512, 511, 0);
    gemm_bt2<1, false, true,  true, false><<<dim3(2, 512), 256, 0, stream>>>(
        hbuf, WcT, bc, pv, 256, 256, 256, 256, 255, 0);

    // lag correlation
    gemm_bt2<1, false, false, false, true><<<dim3(4, 4, 36), 256, 0, stream>>>(
        a_bf, pv, nullptr, partial, 32768, 32768, 512, 8192, 32767, 512);

    reduce_max9<<<dim3(1024), 256, 0, stream>>>(partial, out);
}

// Round 3
// 543.542 us; speedup vs baseline: 1.2586x; 1.0782x over previous
//
#include <hip/hip_runtime.h>
#include <cstdint>
#include <cstddef>

typedef __attribute__((ext_vector_type(8))) short frag8;
typedef __attribute__((ext_vector_type(4))) float f32x4;

static __device__ __forceinline__ unsigned short f2bf(float f) {
    unsigned int u = __float_as_uint(f);
    u += 0x7fffu + ((u >> 16) & 1u);
    return (unsigned short)(u >> 16);
}

// async global->LDS, 16B per lane. LDS dest = wave-uniform base + lane*16.
static __device__ __forceinline__ void gll16(const void* g, void* l) {
    __builtin_amdgcn_global_load_lds(
        (const __attribute__((address_space(1))) unsigned int*)g,
        (__attribute__((address_space(3))) unsigned int*)l, 16, 0, 0);
}

#define CST 136   // C-stage LDS row stride (ushorts); 136*2=272 keeps 16B align, spreads banks

// ---------------- MLP GEMM (BK=32), audio+video batched via blockIdx.z -----------
// C[M,256] = act(A[M,K] @ Bt[256,K]^T + bias), output bf16 via LDS-packed stores.
// AMODE 0: A fp32 (convert in staging). AMODE 1: A bf16 via swizzled global_load_lds.
template<int AMODE, bool RELU>
__global__ __launch_bounds__(256, 2)
void gemm_mlp(const void* __restrict__ A0, const void* __restrict__ A1,
              const unsigned short* __restrict__ B0, const unsigned short* __restrict__ B1,
              const float* __restrict__ bias0, const float* __restrict__ bias1,
              unsigned short* __restrict__ C0, unsigned short* __restrict__ C1,
              int ldA, int kLen)
{
    __shared__ __align__(16) char smem[CST * 128 * 2];   // 34816 B, reused for C-stage
    unsigned short* As = (unsigned short*)smem;
    unsigned short* Bs = (unsigned short*)(smem + (AMODE == 0 ? 10240 : 8192));
    unsigned short* Cst = (unsigned short*)smem;

    const void* Av = blockIdx.z ? A1 : A0;
    const unsigned short* Bt = blockIdx.z ? B1 : B0;
    const float* bias = blockIdx.z ? bias1 : bias0;
    unsigned short* Cv = blockIdx.z ? C1 : C0;

    const int t    = threadIdx.x;
    const int wave = t >> 6;
    const int lane = t & 63;
    const int quad = lane >> 4;
    const int l15  = lane & 15;
    const int wm   = (wave >> 1) * 64;
    const int wn   = (wave & 1) * 64;
    const int m0   = blockIdx.y * 128;
    const int n0   = blockIdx.x * 128;

    // gll mapping (4 granules/row): slot s = wave*128 + p*64 + lane
    const int rowL = (wave << 5) + (lane >> 2);
    const int qL   = (lane & 3) ^ ((lane >> 3) & 3);
    const size_t offB0 = (size_t)(n0 + rowL) * kLen + qL * 8;   // ldB == kLen
    const size_t offA0 = (size_t)(m0 + rowL) * ldA + qL * 8;
    const int swz = quad ^ ((l15 >> 1) & 3);

    f32x4 acc[4][4];
    #pragma unroll
    for (int i = 0; i < 4; ++i)
        #pragma unroll
        for (int j = 0; j < 4; ++j)
            acc[i][j] = (f32x4){0.f, 0.f, 0.f, 0.f};

    for (int k0 = 0; k0 < kLen; k0 += 32) {
        gll16(Bt + offB0 + k0, &Bs[wave * 1024]);
        gll16(Bt + offB0 + (size_t)16 * kLen + k0, &Bs[wave * 1024 + 512]);
        if (AMODE == 1) {
            const unsigned short* A = (const unsigned short*)Av;
            gll16(A + offA0 + k0, &As[wave * 1024]);
            gll16(A + offA0 + (size_t)16 * ldA + k0, &As[wave * 1024 + 512]);
        } else {
            const float* A = (const float*)Av;
            #pragma unroll
            for (int p = 0; p < 4; ++p) {
                int idx = p * 256 + t;
                int row = idx >> 3;
                int col = (idx & 7) * 4;
                const float4 v = *(const float4*)(A + (size_t)(m0 + row) * ldA + (k0 + col));
                unsigned int u0 = (unsigned int)f2bf(v.x) | ((unsigned int)f2bf(v.y) << 16);
                unsigned int u1 = (unsigned int)f2bf(v.z) | ((unsigned int)f2bf(v.w) << 16);
                uint2 pk; pk.x = u0; pk.y = u1;
                *(uint2*)&As[row * 40 + col] = pk;
            }
        }
        __syncthreads();

        frag8 af[4], bf[4];
        #pragma unroll
        for (int i = 0; i < 4; ++i) {
            const int row = wm + i * 16 + l15;
            if (AMODE == 0)
                af[i] = *(const frag8*)&As[row * 40 + quad * 8];
            else
                af[i] = *(const frag8*)&As[(row * 4 + swz) * 8];
        }
        #pragma unroll
        for (int j = 0; j < 4; ++j) {
            const int row = wn + j * 16 + l15;
            bf[j] = *(const frag8*)&Bs[(row * 4 + swz) * 8];
        }
        #pragma unroll
        for (int i = 0; i < 4; ++i)
            #pragma unroll
            for (int j = 0; j < 4; ++j)
                acc[i][j] = __builtin_amdgcn_mfma_f32_16x16x32_bf16(af[i], bf[j], acc[i][j], 0, 0, 0);
        __syncthreads();
    }

    // epilogue: bias/act -> bf16 C-stage in LDS -> coalesced 16B stores
    #pragma unroll
    for (int i = 0; i < 4; ++i) {
        const int rl = wm + i * 16 + quad * 4;
        #pragma unroll
        for (int j = 0; j < 4; ++j) {
            const int cl = wn + j * 16 + l15;
            const float bv = bias[n0 + cl];
            #pragma unroll
            for (int r = 0; r < 4; ++r) {
                float val = acc[i][j][r] + bv;
                if (RELU) val = fmaxf(val, 0.0f);
                Cst[(rl + r) * CST + cl] = f2bf(val);
            }
        }
    }
    __syncthreads();
    #pragma unroll
    for (int u = 0; u < 8; ++u) {
        const int c   = u * 256 + t;     // 16B chunk id, 0..2047
        const int row = c >> 4;
        const int c8  = (c & 15) * 8;
        uint4 v = *(const uint4*)&Cst[row * CST + c8];
        *(uint4*)&Cv[(size_t)(m0 + row) * 256 + n0 + c8] = v;
    }
}

// ---------------- lag correlation GEMM (BK=64) ------------------------------------
// partial[z][q][c] = A[128q-tile, kchunk] @ B[128c-tile, kchunk(shifted)]^T
// z = dz*4+ks; delta = dz-4; B k-index circularly shifted by -256*delta mod 32768.
__global__ __launch_bounds__(256, 2)
void gemm_corr(const unsigned short* __restrict__ A, const unsigned short* __restrict__ B,
               float* __restrict__ partial)
{
    __shared__ __align__(16) unsigned short As[128 * 64];
    __shared__ __align__(16) unsigned short Bs[128 * 64];

    const int t    = threadIdx.x;
    const int wave = t >> 6;
    const int lane = t & 63;
    const int quad = lane >> 4;
    const int l15  = lane & 15;
    const int wm   = (wave >> 1) * 64;
    const int wn   = (wave & 1) * 64;
    const int m0   = blockIdx.y * 128;
    const int n0   = blockIdx.x * 128;

    const int z      = blockIdx.z;
    const int kStart = (z & 3) * 8192;
    const int delta  = (z >> 2) - 4;
    const int koff   = (32768 - 256 * delta) & 32767;

    // gll mapping (8 granules/row): slot s = wave*256 + p*64 + lane
    // row = wave*32 + p*8 + (lane>>3); stored granule g = lane&7 holds src granule g ^ (row&7)
    const int rowL = (wave << 5) + (lane >> 3);
    const int qL   = (lane & 7) ^ ((lane >> 3) & 7);
    const size_t aBase = (size_t)(m0 + rowL) * 32768 + qL * 8;
    const size_t bBase = (size_t)(n0 + rowL) * 32768 + qL * 8;
    unsigned short* AsW = As + wave * 2048;
    unsigned short* BsW = Bs + wave * 2048;
    const int swz = l15 & 7;

    f32x4 acc[4][4];
    #pragma unroll
    for (int i = 0; i < 4; ++i)
        #pragma unroll
        for (int j = 0; j < 4; ++j)
            acc[i][j] = (f32x4){0.f, 0.f, 0.f, 0.f};

    for (int k0 = 0; k0 < 8192; k0 += 64) {
        const int kA = kStart + k0;
        const int kB = (kA + koff) & 32767;
        #pragma unroll
        for (int p = 0; p < 4; ++p) {
            gll16(A + aBase + (size_t)(p * 8) * 32768 + kA, AsW + p * 512);
            gll16(B + bBase + (size_t)(p * 8) * 32768 + kB, BsW + p * 512);
        }
        __syncthreads();

        frag8 af[2][4], bf[2][4];
        #pragma unroll
        for (int i = 0; i < 4; ++i) {
            const int row = wm + i * 16 + l15;
            #pragma unroll
            for (int kh = 0; kh < 2; ++kh)
                af[kh][i] = *(const frag8*)&As[row * 64 + (((kh * 4 + quad) ^ swz) * 8)];
        }
        #pragma unroll
        for (int j = 0; j < 4; ++j) {
            const int row = wn + j * 16 + l15;
            #pragma unroll
            for (int kh = 0; kh < 2; ++kh)
                bf[kh][j] = *(const frag8*)&Bs[row * 64 + (((kh * 4 + quad) ^ swz) * 8)];
        }
        #pragma unroll
        for (int kh = 0; kh < 2; ++kh)
            #pragma unroll
            for (int i = 0; i < 4; ++i)
                #pragma unroll
                for (int j = 0; j < 4; ++j)
                    acc[i][j] = __builtin_amdgcn_mfma_f32_16x16x32_bf16(af[kh][i], bf[kh][j], acc[i][j], 0, 0, 0);
        __syncthreads();
    }

    float* C = partial + (size_t)z * 262144;
    #pragma unroll
    for (int i = 0; i < 4; ++i) {
        const int rg = m0 + wm + i * 16 + quad * 4;
        #pragma unroll
        for (int j = 0; j < 4; ++j) {
            const int cg = n0 + wn + j * 16 + l15;
            #pragma unroll
            for (int r = 0; r < 4; ++r)
                C[(size_t)(rg + r) * 512 + cg] = acc[i][j][r];
        }
    }
}

// ---------------- prep: all weight transposes + Wc fold in ONE dispatch -----------
__global__ void prep(const float* __restrict__ a_w1, const float* __restrict__ v_w1,
                     const float* __restrict__ a_w2, const float* __restrict__ v_w2,
                     const float* __restrict__ W, const float* __restrict__ v_b2,
                     unsigned short* __restrict__ aw1T, unsigned short* __restrict__ vw1T,
                     unsigned short* __restrict__ aw2T,
                     unsigned short* __restrict__ WcT, float* __restrict__ bc)
{
    const int b = blockIdx.x;
    __shared__ float tl[32][33];
    __shared__ float wcol[256];
    if (b < 320) {
        const float* src; unsigned short* dst; int R, C, tile;
        if (b < 128)      { src = a_w1; dst = aw1T; R = 512; C = 256; tile = b; }
        else if (b < 256) { src = v_w1; dst = vw1T; R = 512; C = 256; tile = b - 128; }
        else              { src = a_w2; dst = aw2T; R = 256; C = 256; tile = b - 256; }
        const int tilesX = C / 32;
        const int bx = (tile % tilesX) * 32, by = (tile / tilesX) * 32;
        const int tx = threadIdx.x & 31, ty = threadIdx.x >> 5;
        #pragma unroll
        for (int r = ty; r < 32; r += 8)
            tl[r][tx] = src[(size_t)(by + r) * C + bx + tx];
        __syncthreads();
        #pragma unroll
        for (int c = ty; c < 32; c += 8)
            dst[(size_t)(bx + c) * R + by + tx] = f2bf(tl[tx][c]);
    } else {
        // WcT[n][k] = sum_d v_w2[k][d] * W[d][n]; bc[n] = sum_d v_b2[d]*W[d][n]
        const int n = b - 320, k = threadIdx.x;
        wcol[k] = W[(size_t)k * 256 + n];
        __syncthreads();
        float s = 0.f;
        #pragma unroll 8
        for (int d = 0; d < 256; ++d) s += v_w2[(size_t)k * 256 + d] * wcol[d];
        WcT[(size_t)n * 256 + k] = f2bf(s);
        if (k == 0) {
            float tt = 0.f;
            for (int d = 0; d < 256; ++d) tt += v_b2[d] * wcol[d];
            bc[n] = tt;
        }
    }
}

// out[q,c] = max_dz sum_ks partial[(dz*4+ks)][q*512+c]
__global__ void reduce_max9(const float* __restrict__ partial, float* __restrict__ out) {
    const int idx = blockIdx.x * blockDim.x + threadIdx.x;
    float best = -3.4e38f;
    #pragma unroll
    for (int dz = 0; dz < 9; ++dz) {
        float s = 0.f;
        #pragma unroll
        for (int ks = 0; ks < 4; ++ks)
            s += partial[((size_t)(dz * 4 + ks) << 18) + idx];
        best = fmaxf(best, s);
    }
    out[idx] = best;
}

extern "C" void kernel_launch(void* const* d_in, const int* in_sizes, int n_in,
                              void* d_out, int out_size, void* d_ws, size_t ws_size,
                              hipStream_t stream) {
    const float* audio = (const float*)d_in[0];
    const float* video = (const float*)d_in[1];
    const float* a_w1  = (const float*)d_in[2];
    const float* a_b1  = (const float*)d_in[3];
    const float* a_w2  = (const float*)d_in[4];
    const float* a_b2  = (const float*)d_in[5];
    const float* v_w1  = (const float*)d_in[6];
    const float* v_b1  = (const float*)d_in[7];
    const float* v_w2  = (const float*)d_in[8];
    const float* v_b2  = (const float*)d_in[9];
    const float* Wm    = (const float*)d_in[10];

    char* ws = (char*)d_ws;
    unsigned short* aw1T = (unsigned short*)(ws + 0);          // [256][512]
    unsigned short* vw1T = (unsigned short*)(ws + 262144);     // [256][512]
    unsigned short* aw2T = (unsigned short*)(ws + 524288);     // [256][256]
    unsigned short* WcT  = (unsigned short*)(ws + 655360);     // [256][256]
    float*          bc   = (float*)(ws + 786432);              // [256]
    unsigned short* a_bf = (unsigned short*)(ws + 1048576);    // [512][32768] bf16
    unsigned short* pv   = (unsigned short*)(ws + 34603008);   // [512][32768] bf16
    unsigned short* h_a  = (unsigned short*)(ws + 68157440);   // [65536][256] bf16 (dead before corr)
    unsigned short* h_v  = (unsigned short*)(ws + 101711872);  // [65536][256] bf16 (dead before corr)
    float* partial       = (float*)(ws + 68157440);            // [36][512][512] fp32 (over dead h)
    float* out = (float*)d_out;

    // 1: all weight prep
    prep<<<dim3(576), 256, 0, stream>>>(a_w1, v_w1, a_w2, v_w2, Wm, v_b2,
                                        aw1T, vw1T, aw2T, WcT, bc);
    // 2: layer-1 both modalities (fp32 in, bf16 out)
    gemm_mlp<0, true><<<dim3(2, 512, 2), 256, 0, stream>>>(
        audio, video, aw1T, vw1T, a_b1, v_b1, h_a, h_v, 512, 512);
    // 3: layer-2 both (audio: w2; video: w2@W fold)
    gemm_mlp<1, false><<<dim3(2, 512, 2), 256, 0, stream>>>(
        h_a, h_v, aw2T, WcT, a_b2, bc, a_bf, pv, 256, 256);
    // 4: lag correlation
    gemm_corr<<<dim3(4, 4, 36), 256, 0, stream>>>(a_bf, pv, partial);
    // 5: split-K sum + max over deltas
    reduce_max9<<<dim3(1024), 256, 0, stream>>>(partial, out);
}

// Round 4
// 499.669 us; speedup vs baseline: 1.3691x; 1.0878x over previous
//
#include <hip/hip_runtime.h>
#include <cstdint>
#include <cstddef>

typedef __attribute__((ext_vector_type(8))) short frag8;
typedef __attribute__((ext_vector_type(4))) float f32x4;

static __device__ __forceinline__ unsigned short f2bf_r(float f) {
    return (unsigned short)((__float_as_uint(f) + 0x8000u) >> 16);   // round-half-up
}

// async global->LDS, 16B per lane. LDS dest = wave-uniform base + lane*16.
static __device__ __forceinline__ void gll16(const void* g, void* l) {
    __builtin_amdgcn_global_load_lds(
        (const __attribute__((address_space(1))) unsigned int*)g,
        (__attribute__((address_space(3))) unsigned int*)l, 16, 0, 0);
}

// ---------------- fused MLP: out = relu(X@W1+b1)@W2' + b2' ----------------------
// X fp32 [65536][512]; W1T bf16 [256][512]; W2T bf16 [256][256]; out bf16 [65536][256].
// Block: 64 M-rows x full N=256. h tile lives in LDS (never hits HBM).
// blockIdx.y selects modality (0=audio, 1=video w/ W2@W fold).
__global__ __launch_bounds__(256, 2)
void mlp_fused(const float* __restrict__ X0, const float* __restrict__ X1,
               const unsigned short* __restrict__ W1T0, const unsigned short* __restrict__ W1T1,
               const float* __restrict__ b1v0, const float* __restrict__ b1v1,
               const unsigned short* __restrict__ W2T0, const unsigned short* __restrict__ W2T1,
               const float* __restrict__ b2v0, const float* __restrict__ b2v1,
               unsigned short* __restrict__ O0, unsigned short* __restrict__ O1)
{
    __shared__ __align__(16) unsigned short As[64 * 72];     // 9216 B (fp32-staged A, pad 72)
    __shared__ __align__(16) unsigned short Bs[256 * 64];    // 32768 B (weight tile, swizzled)
    __shared__ __align__(16) unsigned short hs[64 * 264];    // 33792 B (h tile / C-stage)

    const int mod = blockIdx.y;
    const float* X = mod ? X1 : X0;
    const unsigned short* W1T = mod ? W1T1 : W1T0;
    const unsigned short* W2T = mod ? W2T1 : W2T0;
    const float* b1 = mod ? b1v1 : b1v0;
    const float* b2 = mod ? b2v1 : b2v0;
    unsigned short* O = mod ? O1 : O0;

    const int t    = threadIdx.x;
    const int wave = t >> 6;
    const int lane = t & 63;
    const int quad = lane >> 4;
    const int l15  = lane & 15;
    const int m0   = blockIdx.x * 64;

    // gll B mapping (8 granules/row, xor-swizzle: stored g holds src g ^ (row&7))
    const int rowB = lane >> 3;                 // 0..7
    const int qB   = (lane & 7) ^ rowB;
    const int nRowBase = wave * 64 + rowB;      // +p*8 per call
    unsigned short* BsW = Bs + wave * 4096;     // 8 calls x 512 ush
    const int swz = l15 & 7;

    f32x4 acc[4][4];
    #pragma unroll
    for (int i = 0; i < 4; ++i)
        #pragma unroll
        for (int j = 0; j < 4; ++j)
            acc[i][j] = (f32x4){0.f, 0.f, 0.f, 0.f};

    // ---------------- phase 1: h = relu(X@W1+b1), K=512, BK=64 ----------------
    for (int k0 = 0; k0 < 512; k0 += 64) {
        #pragma unroll
        for (int p = 0; p < 4; ++p) {           // stage A 64x64 fp32 -> bf16
            const int idx = p * 256 + t;
            const int row = idx >> 4;
            const int col = (idx & 15) * 4;
            const float4 v = *(const float4*)(X + (size_t)(m0 + row) * 512 + k0 + col);
            const unsigned int a0 = __float_as_uint(v.x) + 0x8000u;
            const unsigned int a1 = __float_as_uint(v.y) + 0x8000u;
            const unsigned int a2 = __float_as_uint(v.z) + 0x8000u;
            const unsigned int a3 = __float_as_uint(v.w) + 0x8000u;
            uint2 pk;
            pk.x = __builtin_amdgcn_perm(a1, a0, 0x07060302u);
            pk.y = __builtin_amdgcn_perm(a3, a2, 0x07060302u);
            *(uint2*)&As[row * 72 + col] = pk;
        }
        #pragma unroll
        for (int p = 0; p < 8; ++p)             // stage W1T 256x64 bf16
            gll16(W1T + (size_t)(nRowBase + p * 8) * 512 + qB * 8 + k0, BsW + p * 512);
        __syncthreads();

        frag8 af[2][4], bf[2][4];
        #pragma unroll
        for (int i = 0; i < 4; ++i)
            #pragma unroll
            for (int kh = 0; kh < 2; ++kh)
                af[kh][i] = *(const frag8*)&As[(i * 16 + l15) * 72 + kh * 32 + quad * 8];
        #pragma unroll
        for (int j = 0; j < 4; ++j) {
            const int row = wave * 64 + j * 16 + l15;
            #pragma unroll
            for (int kh = 0; kh < 2; ++kh)
                bf[kh][j] = *(const frag8*)&Bs[row * 64 + (((kh * 4 + quad) ^ swz) * 8)];
        }
        #pragma unroll
        for (int kh = 0; kh < 2; ++kh)
            #pragma unroll
            for (int i = 0; i < 4; ++i)
                #pragma unroll
                for (int j = 0; j < 4; ++j)
                    acc[i][j] = __builtin_amdgcn_mfma_f32_16x16x32_bf16(af[kh][i], bf[kh][j], acc[i][j], 0, 0, 0);
        __syncthreads();
    }

    // h -> LDS (bias + relu + bf16), C-layout scatter
    #pragma unroll
    for (int j = 0; j < 4; ++j) {
        const int col = wave * 64 + j * 16 + l15;
        const float bv = b1[col];
        #pragma unroll
        for (int i = 0; i < 4; ++i) {
            const int rl = i * 16 + quad * 4;
            #pragma unroll
            for (int r = 0; r < 4; ++r)
                hs[(rl + r) * 264 + col] = f2bf_r(fmaxf(acc[i][j][r] + bv, 0.0f));
        }
    }
    __syncthreads();

    // ---------------- phase 2: out = h@W2' + b2', K=256, BK=64 ----------------
    #pragma unroll
    for (int i = 0; i < 4; ++i)
        #pragma unroll
        for (int j = 0; j < 4; ++j)
            acc[i][j] = (f32x4){0.f, 0.f, 0.f, 0.f};

    for (int k0 = 0; k0 < 256; k0 += 64) {
        #pragma unroll
        for (int p = 0; p < 8; ++p)
            gll16(W2T + (size_t)(nRowBase + p * 8) * 256 + qB * 8 + k0, BsW + p * 512);
        __syncthreads();

        frag8 af[2][4], bf[2][4];
        #pragma unroll
        for (int i = 0; i < 4; ++i)
            #pragma unroll
            for (int kh = 0; kh < 2; ++kh)
                af[kh][i] = *(const frag8*)&hs[(i * 16 + l15) * 264 + k0 + kh * 32 + quad * 8];
        #pragma unroll
        for (int j = 0; j < 4; ++j) {
            const int row = wave * 64 + j * 16 + l15;
            #pragma unroll
            for (int kh = 0; kh < 2; ++kh)
                bf[kh][j] = *(const frag8*)&Bs[row * 64 + (((kh * 4 + quad) ^ swz) * 8)];
        }
        #pragma unroll
        for (int kh = 0; kh < 2; ++kh)
            #pragma unroll
            for (int i = 0; i < 4; ++i)
                #pragma unroll
                for (int j = 0; j < 4; ++j)
                    acc[i][j] = __builtin_amdgcn_mfma_f32_16x16x32_bf16(af[kh][i], bf[kh][j], acc[i][j], 0, 0, 0);
        __syncthreads();
    }

    // out epilogue: bias + bf16 -> hs C-stage -> coalesced 16B stores
    #pragma unroll
    for (int j = 0; j < 4; ++j) {
        const int col = wave * 64 + j * 16 + l15;
        const float bv = b2[col];
        #pragma unroll
        for (int i = 0; i < 4; ++i) {
            const int rl = i * 16 + quad * 4;
            #pragma unroll
            for (int r = 0; r < 4; ++r)
                hs[(rl + r) * 264 + col] = f2bf_r(acc[i][j][r] + bv);
        }
    }
    __syncthreads();
    #pragma unroll
    for (int u = 0; u < 8; ++u) {
        const int chunk = u * 256 + t;          // 0..2047 16B chunks
        const int row = chunk >> 5;
        const int c16 = (chunk & 31) * 8;
        uint4 v = *(const uint4*)&hs[row * 264 + c16];
        *(uint4*)&O[(size_t)(m0 + row) * 256 + c16] = v;
    }
}

// ---------------- lag correlation GEMM (BK=64) ------------------------------------
__global__ __launch_bounds__(256, 2)
void gemm_corr(const unsigned short* __restrict__ A, const unsigned short* __restrict__ B,
               float* __restrict__ partial)
{
    __shared__ __align__(16) unsigned short As[128 * 64];
    __shared__ __align__(16) unsigned short Bs[128 * 64];

    const int t    = threadIdx.x;
    const int wave = t >> 6;
    const int lane = t & 63;
    const int quad = lane >> 4;
    const int l15  = lane & 15;
    const int wm   = (wave >> 1) * 64;
    const int wn   = (wave & 1) * 64;
    const int m0   = blockIdx.y * 128;
    const int n0   = blockIdx.x * 128;

    const int z      = blockIdx.z;
    const int kStart = (z & 3) * 8192;
    const int delta  = (z >> 2) - 4;
    const int koff   = (32768 - 256 * delta) & 32767;

    const int rowL = (wave << 5) + (lane >> 3);
    const int qL   = (lane & 7) ^ ((lane >> 3) & 7);
    const size_t aBase = (size_t)(m0 + rowL) * 32768 + qL * 8;
    const size_t bBase = (size_t)(n0 + rowL) * 32768 + qL * 8;
    unsigned short* AsW = As + wave * 2048;
    unsigned short* BsW = Bs + wave * 2048;
    const int swz = l15 & 7;

    f32x4 acc[4][4];
    #pragma unroll
    for (int i = 0; i < 4; ++i)
        #pragma unroll
        for (int j = 0; j < 4; ++j)
            acc[i][j] = (f32x4){0.f, 0.f, 0.f, 0.f};

    for (int k0 = 0; k0 < 8192; k0 += 64) {
        const int kA = kStart + k0;
        const int kB = (kA + koff) & 32767;
        #pragma unroll
        for (int p = 0; p < 4; ++p) {
            gll16(A + aBase + (size_t)(p * 8) * 32768 + kA, AsW + p * 512);
            gll16(B + bBase + (size_t)(p * 8) * 32768 + kB, BsW + p * 512);
        }
        __syncthreads();

        frag8 af[2][4], bf[2][4];
        #pragma unroll
        for (int i = 0; i < 4; ++i) {
            const int row = wm + i * 16 + l15;
            #pragma unroll
            for (int kh = 0; kh < 2; ++kh)
                af[kh][i] = *(const frag8*)&As[row * 64 + (((kh * 4 + quad) ^ swz) * 8)];
        }
        #pragma unroll
        for (int j = 0; j < 4; ++j) {
            const int row = wn + j * 16 + l15;
            #pragma unroll
            for (int kh = 0; kh < 2; ++kh)
                bf[kh][j] = *(const frag8*)&Bs[row * 64 + (((kh * 4 + quad) ^ swz) * 8)];
        }
        #pragma unroll
        for (int kh = 0; kh < 2; ++kh)
            #pragma unroll
            for (int i = 0; i < 4; ++i)
                #pragma unroll
                for (int j = 0; j < 4; ++j)
                    acc[i][j] = __builtin_amdgcn_mfma_f32_16x16x32_bf16(af[kh][i], bf[kh][j], acc[i][j], 0, 0, 0);
        __syncthreads();
    }

    float* C = partial + (size_t)z * 262144;
    #pragma unroll
    for (int i = 0; i < 4; ++i) {
        const int rg = m0 + wm + i * 16 + quad * 4;
        #pragma unroll
        for (int j = 0; j < 4; ++j) {
            const int cg = n0 + wn + j * 16 + l15;
            #pragma unroll
            for (int r = 0; r < 4; ++r)
                C[(size_t)(rg + r) * 512 + cg] = acc[i][j][r];
        }
    }
}

// ---------------- prep: weight transposes + Wc fold in one dispatch ---------------
__global__ void prep(const float* __restrict__ a_w1, const float* __restrict__ v_w1,
                     const float* __restrict__ a_w2, const float* __restrict__ v_w2,
                     const float* __restrict__ W, const float* __restrict__ v_b2,
                     unsigned short* __restrict__ aw1T, unsigned short* __restrict__ vw1T,
                     unsigned short* __restrict__ aw2T,
                     unsigned short* __restrict__ WcT, float* __restrict__ bc)
{
    const int b = blockIdx.x;
    __shared__ float tl[32][33];
    __shared__ float wcol[256];
    if (b < 320) {
        const float* src; unsigned short* dst; int R, C, tile;
        if (b < 128)      { src = a_w1; dst = aw1T; R = 512; C = 256; tile = b; }
        else if (b < 256) { src = v_w1; dst = vw1T; R = 512; C = 256; tile = b - 128; }
        else              { src = a_w2; dst = aw2T; R = 256; C = 256; tile = b - 256; }
        const int tilesX = C / 32;
        const int bx = (tile % tilesX) * 32, by = (tile / tilesX) * 32;
        const int tx = threadIdx.x & 31, ty = threadIdx.x >> 5;
        #pragma unroll
        for (int r = ty; r < 32; r += 8)
            tl[r][tx] = src[(size_t)(by + r) * C + bx + tx];
        __syncthreads();
        #pragma unroll
        for (int c = ty; c < 32; c += 8)
            dst[(size_t)(bx + c) * R + by + tx] = f2bf_r(tl[tx][c]);
    } else {
        const int n = b - 320, k = threadIdx.x;
        wcol[k] = W[(size_t)k * 256 + n];
        __syncthreads();
        float s = 0.f;
        #pragma unroll 8
        for (int d = 0; d < 256; ++d) s += v_w2[(size_t)k * 256 + d] * wcol[d];
        WcT[(size_t)n * 256 + k] = f2bf_r(s);
        if (k == 0) {
            float tt = 0.f;
            for (int d = 0; d < 256; ++d) tt += v_b2[d] * wcol[d];
            bc[n] = tt;
        }
    }
}

__global__ void reduce_max9(const float* __restrict__ partial, float* __restrict__ out) {
    const int idx = blockIdx.x * blockDim.x + threadIdx.x;
    float best = -3.4e38f;
    #pragma unroll
    for (int dz = 0; dz < 9; ++dz) {
        float s = 0.f;
        #pragma unroll
        for (int ks = 0; ks < 4; ++ks)
            s += partial[((size_t)(dz * 4 + ks) << 18) + idx];
        best = fmaxf(best, s);
    }
    out[idx] = best;
}

extern "C" void kernel_launch(void* const* d_in, const int* in_sizes, int n_in,
                              void* d_out, int out_size, void* d_ws, size_t ws_size,
                              hipStream_t stream) {
    const float* audio = (const float*)d_in[0];
    const float* video = (const float*)d_in[1];
    const float* a_w1  = (const float*)d_in[2];
    const float* a_b1  = (const float*)d_in[3];
    const float* a_w2  = (const float*)d_in[4];
    const float* a_b2  = (const float*)d_in[5];
    const float* v_w1  = (const float*)d_in[6];
    const float* v_b1  = (const float*)d_in[7];
    const float* v_w2  = (const float*)d_in[8];
    const float* v_b2  = (const float*)d_in[9];
    const float* Wm    = (const float*)d_in[10];

    char* ws = (char*)d_ws;
    unsigned short* aw1T = (unsigned short*)(ws + 0);          // [256][512]
    unsigned short* vw1T = (unsigned short*)(ws + 262144);     // [256][512]
    unsigned short* aw2T = (unsigned short*)(ws + 524288);     // [256][256]
    unsigned short* WcT  = (unsigned short*)(ws + 655360);     // [256][256]
    float*          bc   = (float*)(ws + 786432);              // [256]
    unsigned short* a_bf = (unsigned short*)(ws + 1048576);    // [512][32768] bf16
    unsigned short* pv   = (unsigned short*)(ws + 34603008);   // [512][32768] bf16
    float* partial       = (float*)(ws + 68157440);            // [36][512][512] fp32
    float* out = (float*)d_out;

    // 1: weight prep
    prep<<<dim3(576), 256, 0, stream>>>(a_w1, v_w1, a_w2, v_w2, Wm, v_b2,
                                        aw1T, vw1T, aw2T, WcT, bc);
    // 2: fused two-layer MLP, both modalities (h never leaves LDS)
    mlp_fused<<<dim3(1024, 2), 256, 0, stream>>>(
        audio, video, aw1T, vw1T, a_b1, v_b1, aw2T, WcT, a_b2, bc, a_bf, pv);
    // 3: lag correlation
    gemm_corr<<<dim3(4, 4, 36), 256, 0, stream>>>(a_bf, pv, partial);
    // 4: split-K sum + max over deltas
    reduce_max9<<<dim3(1024), 256, 0, stream>>>(partial, out);
}